// Round 18
// baseline (67.302 us; speedup 1.0000x reference)
//
#include <hip/hip_runtime.h>
#include <hip/hip_bf16.h>

#define IN_F 8192
#define OUT_F 8192
#define NROWS 128
#define CB 256
#define NSL2 16                // K-slices (grid.y)
#define NSLT 16                // partial slices summed by k_post
#define KSLICE2 (IN_F / NSL2)  // 512
#define NTB 128                // n-tile per block
#define QC (IN_F / 8)          // 1024 dwords per Qidxs row

using bf8   = __attribute__((ext_vector_type(8))) short;  // 8 bf16 (4 VGPRs)
using f32x4 = __attribute__((ext_vector_type(4))) float;  // 4 fp32 accum

__device__ inline float bf2f(unsigned int u) {
    union { unsigned int i; float f; } v; v.i = u << 16; return v.f;
}
__device__ inline unsigned short f2bf(float f) {
    __hip_bfloat16 h = __float2bfloat16(f);
    return *reinterpret_cast<unsigned short*>(&h);
}
__device__ inline void unpack8(uint4 v, float* f) {
    f[0] = bf2f(v.x & 0xffffu); f[1] = bf2f(v.x >> 16);
    f[2] = bf2f(v.y & 0xffffu); f[3] = bf2f(v.y >> 16);
    f[4] = bf2f(v.z & 0xffffu); f[5] = bf2f(v.z >> 16);
    f[6] = bf2f(v.w & 0xffffu); f[7] = bf2f(v.w >> 16);
}

#define FWHT_SCALE 0.011048543456039806f  // 1/sqrt(8192)

// ---------------- FWHT-4096 on 256 threads x 16 elems (round-11 proven) ----
#define FWHT16(v)                                                         \
    _Pragma("unroll")                                                     \
    for (int hb = 0; hb < 4; ++hb) {                                      \
        const int hh = 1 << hb;                                           \
        _Pragma("unroll")                                                 \
        for (int j = 0; j < 16; ++j)                                      \
            if (!(j & hh)) {                                              \
                float a_ = v[j], b_ = v[j | hh];                          \
                v[j] = a_ + b_; v[j | hh] = a_ - b_;                      \
            }                                                             \
    }

__device__ inline void fwht4096(float* v, float* lds, int t) {
    FWHT16(v)
#pragma unroll
    for (int e = 0; e < 16; ++e) lds[e * 260 + t] = v[e];
    __syncthreads();
    {
        const int base = (t & 15) * 260 + (t >> 4) * 16;
#pragma unroll
        for (int q = 0; q < 4; ++q) {
            float4 f = *reinterpret_cast<const float4*>(&lds[base + q * 4]);
            v[q * 4 + 0] = f.x; v[q * 4 + 1] = f.y;
            v[q * 4 + 2] = f.z; v[q * 4 + 3] = f.w;
        }
    }
    FWHT16(v)
    __syncthreads();
    {
        const int e = t & 15, ub = t >> 4;
#pragma unroll
        for (int i = 0; i < 16; ++i) lds[e * 260 + i * 16 + ub] = v[i];
    }
    __syncthreads();
    {
        const int e = t & 15, i = t >> 4;
#pragma unroll
        for (int ub = 0; ub < 16; ++ub) v[ub] = lds[e * 260 + i * 16 + ub];
    }
    FWHT16(v)
    __syncthreads();
    {
        const int e = t & 15, i = t >> 4;
#pragma unroll
        for (int ub = 0; ub < 16; ++ub) lds[ub * 260 + i * 16 + e] = v[ub];
    }
    __syncthreads();
    {
        const int base = (t >> 4) * 260 + (t & 15) * 16;
#pragma unroll
        for (int q = 0; q < 4; ++q) {
            float4 f = *reinterpret_cast<const float4*>(&lds[base + q * 4]);
            v[q * 4 + 0] = f.x; v[q * 4 + 1] = f.y;
            v[q * 4 + 2] = f.z; v[q * 4 + 3] = f.w;
        }
    }
}

// ---- Kernel A: xt = fwht(input/scaleWH*SU), MFMA-tiled bf16 (r12 proven) --
// Tiled layout: elem (r,k) at ((r>>4)*256 + (k>>5))*512 + ((k&31)>>3)*128
//               + (r&15)*8 + (k&7)   [ushort units]
__global__ __launch_bounds__(256) void k_pre4(const float* __restrict__ in,
                                              const float* __restrict__ scaleWH,
                                              const float* __restrict__ SU,
                                              unsigned short* __restrict__ xt) {
    __shared__ float lds[4160];
    const int r = blockIdx.x, h = blockIdx.y, t = threadIdx.x;
    float v[16];
    const float4* xp = reinterpret_cast<const float4*>(in + (size_t)r * IN_F);
    const float4* sp = reinterpret_cast<const float4*>(scaleWH);
    const float4* up = reinterpret_cast<const float4*>(SU);
#pragma unroll
    for (int q = 0; q < 4; ++q) {
        float4 xl = xp[t * 4 + q],        sl = sp[t * 4 + q],        ul = up[t * 4 + q];
        float4 xh = xp[1024 + t * 4 + q], sh = sp[1024 + t * 4 + q], uh = up[1024 + t * 4 + q];
        float lo0 = xl.x / sl.x * ul.x, hi0 = xh.x / sh.x * uh.x;
        float lo1 = xl.y / sl.y * ul.y, hi1 = xh.y / sh.y * uh.y;
        float lo2 = xl.z / sl.z * ul.z, hi2 = xh.z / sh.z * uh.z;
        float lo3 = xl.w / sl.w * ul.w, hi3 = xh.w / sh.w * uh.w;
        v[q * 4 + 0] = h ? lo0 - hi0 : lo0 + hi0;
        v[q * 4 + 1] = h ? lo1 - hi1 : lo1 + hi1;
        v[q * 4 + 2] = h ? lo2 - hi2 : lo2 + hi2;
        v[q * 4 + 3] = h ? lo3 - hi3 : lo3 + hi3;
    }
    fwht4096(v, lds, t);
    const int ub = t >> 4, i = t & 15;
    const int kblk = h * 128 + ub * 8 + (i >> 1);
    const size_t base = ((size_t)(r >> 4) * 256 + kblk) * 512 + (size_t)(r & 15) * 8;
#pragma unroll
    for (int half = 0; half < 2; ++half) {
        unsigned int w[4];
#pragma unroll
        for (int p = 0; p < 4; ++p) {
            unsigned int lo = f2bf(v[half * 8 + 2 * p]     * FWHT_SCALE);
            unsigned int hi = f2bf(v[half * 8 + 2 * p + 1] * FWHT_SCALE);
            w[p] = lo | (hi << 16);
        }
        const int oct = (i & 1) * 2 + half;
        *reinterpret_cast<uint4*>(xt + base + oct * 128) = make_uint4(w[0], w[1], w[2], w[3]);
    }
}

// ---- Kernel B: register-index GEMM ----
// grid (64, 16); 256 thr = 4 waves (2 mgrp x 2 ngrp); tile 128x128 x K=512.
// Q slice packed to BYTES in LDS (8 KB) once; after one barrier each lane
// pulls ALL its 16 iterations' indices into 16 registers (4 dwords x 4
// n-blocks). K-loop is barrier-free, zero q-LDS-reads: per iter 4 cbl
// gathers (from register-shifted indices) + 4 A b128 (L2) + 16 MFMA.
__global__ __launch_bounds__(256, 3) void k_gemm17(
        const unsigned short* __restrict__ xt,
        const int* __restrict__ Qidxs,
        const float* __restrict__ cb,
        const float* __restrict__ wscale,
        unsigned short* __restrict__ pout) {
    __shared__ __align__(16) unsigned short cbl[CB][8];   // 4 KB
    __shared__ __align__(16) unsigned int Qb[128 * 16];   // 8 KB packed bytes
    const int tid = threadIdx.x;
    const int wave = tid >> 6, lane = tid & 63;
    const int ngrp = wave & 1, mgrp = wave >> 1;
    const int lr = lane & 15, lk8 = lane >> 4;
    const int n0 = blockIdx.x * NTB;
    const int ks0 = blockIdx.y * KSLICE2;
    const int ksb = ks0 >> 5;           // k32-block base in xt tiling
    const int c0 = ks0 >> 3;            // first Qidxs dword col of slice

    // ---- one-time: load 64-col Q slice, pack to bytes, swizzled store ----
    // byte pos(row, slot, itc) = row*64 + slot*16 + ((itc>>2)^(row&3))*4
    //                            + (itc&3);   col = itc*4 + slot
    {
        const int row = tid >> 1, h = tid & 1;
        const int* g = Qidxs + (size_t)(n0 + row) * QC + c0 + h * 32;
        int q[32];
#pragma unroll
        for (int j4 = 0; j4 < 8; ++j4) {
            int4 vv = *reinterpret_cast<const int4*>(g + j4 * 4);
            q[j4 * 4 + 0] = vv.x; q[j4 * 4 + 1] = vv.y;
            q[j4 * 4 + 2] = vv.z; q[j4 * 4 + 3] = vv.w;
        }
#pragma unroll
        for (int s = 0; s < 4; ++s)
#pragma unroll
            for (int a2 = 0; a2 < 2; ++a2) {
                unsigned int D = (unsigned int)(q[(a2 * 4 + 0) * 4 + s] & 255)
                               | ((unsigned int)(q[(a2 * 4 + 1) * 4 + s] & 255) << 8)
                               | ((unsigned int)(q[(a2 * 4 + 2) * 4 + s] & 255) << 16)
                               | ((unsigned int)(q[(a2 * 4 + 3) * 4 + s] & 255) << 24);
                const int a = h * 2 + a2;
                Qb[row * 16 + s * 4 + (a ^ (row & 3))] = D;
            }
    }
    const float wsc = wscale[0];
    for (int e = tid; e < CB * 8; e += 256) cbl[e >> 3][e & 7] = f2bf(cb[e] * wsc);

    f32x4 acc[4][4];
#pragma unroll
    for (int mt = 0; mt < 4; ++mt)
#pragma unroll
        for (int nt = 0; nt < 4; ++nt) acc[mt][nt] = (f32x4){0.f, 0.f, 0.f, 0.f};

    // A base pointers: rowgrp = mgrp*4 + mt (16-row groups), frag 1KB each
    const unsigned short* xw0 = xt + ((size_t)((mgrp * 4 + 0) * 256) + ksb) * 512 + lane * 8;
    const unsigned short* xw1 = xt + ((size_t)((mgrp * 4 + 1) * 256) + ksb) * 512 + lane * 8;
    const unsigned short* xw2 = xt + ((size_t)((mgrp * 4 + 2) * 256) + ksb) * 512 + lane * 8;
    const unsigned short* xw3 = xt + ((size_t)((mgrp * 4 + 3) * 256) + ksb) * 512 + lane * 8;

    __syncthreads();     // Qb + cbl staged (the only barrier)

    // pull ALL indices for this lane's 16 iterations into registers
    unsigned int qr[4][4];
#pragma unroll
    for (int nb = 0; nb < 4; ++nb) {
        const int qrow = ngrp * 64 + nb * 16 + lr;
#pragma unroll
        for (int a = 0; a < 4; ++a)
            qr[nb][a] = Qb[qrow * 16 + lk8 * 4 + (a ^ (qrow & 3))];
    }

#pragma unroll
    for (int i = 0; i < 16; ++i) {
        const int sh = (i & 3) * 8;
        bf8 b0 = *(const bf8*)&cbl[(qr[0][i >> 2] >> sh) & 255][0];
        bf8 b1 = *(const bf8*)&cbl[(qr[1][i >> 2] >> sh) & 255][0];
        bf8 b2 = *(const bf8*)&cbl[(qr[2][i >> 2] >> sh) & 255][0];
        bf8 b3 = *(const bf8*)&cbl[(qr[3][i >> 2] >> sh) & 255][0];
        bf8 a0 = *(const bf8*)(xw0 + (size_t)i * 512);
        bf8 a1 = *(const bf8*)(xw1 + (size_t)i * 512);
        bf8 a2 = *(const bf8*)(xw2 + (size_t)i * 512);
        bf8 a3 = *(const bf8*)(xw3 + (size_t)i * 512);
        acc[0][0] = __builtin_amdgcn_mfma_f32_16x16x32_bf16(a0, b0, acc[0][0], 0, 0, 0);
        acc[0][1] = __builtin_amdgcn_mfma_f32_16x16x32_bf16(a0, b1, acc[0][1], 0, 0, 0);
        acc[0][2] = __builtin_amdgcn_mfma_f32_16x16x32_bf16(a0, b2, acc[0][2], 0, 0, 0);
        acc[0][3] = __builtin_amdgcn_mfma_f32_16x16x32_bf16(a0, b3, acc[0][3], 0, 0, 0);
        acc[1][0] = __builtin_amdgcn_mfma_f32_16x16x32_bf16(a1, b0, acc[1][0], 0, 0, 0);
        acc[1][1] = __builtin_amdgcn_mfma_f32_16x16x32_bf16(a1, b1, acc[1][1], 0, 0, 0);
        acc[1][2] = __builtin_amdgcn_mfma_f32_16x16x32_bf16(a1, b2, acc[1][2], 0, 0, 0);
        acc[1][3] = __builtin_amdgcn_mfma_f32_16x16x32_bf16(a1, b3, acc[1][3], 0, 0, 0);
        acc[2][0] = __builtin_amdgcn_mfma_f32_16x16x32_bf16(a2, b0, acc[2][0], 0, 0, 0);
        acc[2][1] = __builtin_amdgcn_mfma_f32_16x16x32_bf16(a2, b1, acc[2][1], 0, 0, 0);
        acc[2][2] = __builtin_amdgcn_mfma_f32_16x16x32_bf16(a2, b2, acc[2][2], 0, 0, 0);
        acc[2][3] = __builtin_amdgcn_mfma_f32_16x16x32_bf16(a2, b3, acc[2][3], 0, 0, 0);
        acc[3][0] = __builtin_amdgcn_mfma_f32_16x16x32_bf16(a3, b0, acc[3][0], 0, 0, 0);
        acc[3][1] = __builtin_amdgcn_mfma_f32_16x16x32_bf16(a3, b1, acc[3][1], 0, 0, 0);
        acc[3][2] = __builtin_amdgcn_mfma_f32_16x16x32_bf16(a3, b2, acc[3][2], 0, 0, 0);
        acc[3][3] = __builtin_amdgcn_mfma_f32_16x16x32_bf16(a3, b3, acc[3][3], 0, 0, 0);
    }

    // epilogue: C/D col=lane&15, row=(lane>>4)*4+reg; bf16 partial store
    unsigned short* ps = pout + (size_t)blockIdx.y * (NROWS * OUT_F);
#pragma unroll
    for (int mt = 0; mt < 4; ++mt) {
        const int row = mgrp * 64 + mt * 16 + lk8 * 4;
#pragma unroll
        for (int nt = 0; nt < 4; ++nt) {
            const int col = n0 + ngrp * 64 + nt * 16 + lr;
#pragma unroll
            for (int r2 = 0; r2 < 4; ++r2)
                ps[(size_t)(row + r2) * OUT_F + col] = f2bf(acc[mt][nt][r2]);
        }
    }
}

// ---- Kernel C: out = fwht(sum of 16 slices)*SV + bias, grid (128,2) ----
__global__ __launch_bounds__(256) void k_post5(const unsigned short* __restrict__ pin,
                                               const float* __restrict__ SV,
                                               const float* __restrict__ bias,
                                               float* __restrict__ out) {
    __shared__ float lds[4160];
    const int r = blockIdx.x, h = blockIdx.y, t = threadIdx.x;
    float lo[16], hi[16], v[16];
#pragma unroll
    for (int j = 0; j < 16; ++j) { lo[j] = 0.f; hi[j] = 0.f; }
#pragma unroll 1
    for (int sl = 0; sl < NSLT; ++sl) {
        const uint4* pl = reinterpret_cast<const uint4*>(
            pin + (size_t)sl * NROWS * OUT_F + (size_t)r * OUT_F + t * 16);
        const uint4* ph = reinterpret_cast<const uint4*>(
            pin + (size_t)sl * NROWS * OUT_F + (size_t)r * OUT_F + 4096 + t * 16);
        float a[8], b[8];
        unpack8(pl[0], a); unpack8(pl[1], b);
#pragma unroll
        for (int j = 0; j < 8; ++j) { lo[j] += a[j]; lo[8 + j] += b[j]; }
        unpack8(ph[0], a); unpack8(ph[1], b);
#pragma unroll
        for (int j = 0; j < 8; ++j) { hi[j] += a[j]; hi[8 + j] += b[j]; }
    }
#pragma unroll
    for (int j = 0; j < 16; ++j) v[j] = h ? lo[j] - hi[j] : lo[j] + hi[j];
    fwht4096(v, lds, t);
    const int cb4 = (h * 4096 + (t >> 4) * 256 + (t & 15) * 16) >> 2;
    const float4* svp = reinterpret_cast<const float4*>(SV);
    const float4* bip = reinterpret_cast<const float4*>(bias);
    float4* op = reinterpret_cast<float4*>(out + (size_t)r * OUT_F);
#pragma unroll
    for (int q = 0; q < 4; ++q) {
        float4 sv = svp[cb4 + q], bi = bip[cb4 + q], o;
        o.x = v[q * 4 + 0] * FWHT_SCALE * sv.x + bi.x;
        o.y = v[q * 4 + 1] * FWHT_SCALE * sv.y + bi.y;
        o.z = v[q * 4 + 2] * FWHT_SCALE * sv.z + bi.z;
        o.w = v[q * 4 + 3] * FWHT_SCALE * sv.w + bi.w;
        op[cb4 + q] = o;
    }
}

extern "C" void kernel_launch(void* const* d_in, const int* in_sizes, int n_in,
                              void* d_out, int out_size, void* d_ws, size_t ws_size,
                              hipStream_t stream) {
    const float* in      = (const float*)d_in[0];
    const int*   Qidxs   = (const int*)d_in[1];
    const float* cb      = (const float*)d_in[2];
    const float* scaleWH = (const float*)d_in[3];
    const float* SU      = (const float*)d_in[4];
    const float* SV      = (const float*)d_in[5];
    const float* wscale  = (const float*)d_in[6];
    const float* bias    = (const float*)d_in[7];
    float* out = (float*)d_out;

    unsigned short* xt    = (unsigned short*)d_ws;                    // 2 MB (tiled)
    unsigned short* parts = (unsigned short*)((char*)d_ws
                            + (size_t)NROWS * IN_F * 2);              // 32 MB (16 slices)

    k_pre4<<<dim3(NROWS, 2), 256, 0, stream>>>(in, scaleWH, SU, xt);
    k_gemm17<<<dim3(OUT_F / NTB, NSL2), 256, 0, stream>>>(xt, Qidxs, cb, wscale, parts);
    k_post5<<<dim3(NROWS, 2), 256, 0, stream>>>(parts, SV, bias, out);
}

// Round 19
// 55.178 us; speedup vs baseline: 1.2197x; 1.2197x over previous
//
#include <hip/hip_runtime.h>
#include <hip/hip_bf16.h>

#define IN_F 8192
#define OUT_F 8192
#define NROWS 128
#define CB 256
#define NSL2 16                // K-slices (grid.y)
#define NSLT 16                // partial slices summed by k_post
#define KSLICE2 (IN_F / NSL2)  // 512
#define NTB 128                // n-tile per block
#define QC (IN_F / 8)          // 1024 dwords per Qidxs row

using bf8   = __attribute__((ext_vector_type(8))) short;  // 8 bf16 (4 VGPRs)
using f32x4 = __attribute__((ext_vector_type(4))) float;  // 4 fp32 accum

typedef const __attribute__((address_space(1))) void* as1cv;
typedef __attribute__((address_space(3))) void* as3v;

__device__ inline float bf2f(unsigned int u) {
    union { unsigned int i; float f; } v; v.i = u << 16; return v.f;
}
__device__ inline unsigned short f2bf(float f) {
    __hip_bfloat16 h = __float2bfloat16(f);
    return *reinterpret_cast<unsigned short*>(&h);
}
__device__ inline void unpack8(uint4 v, float* f) {
    f[0] = bf2f(v.x & 0xffffu); f[1] = bf2f(v.x >> 16);
    f[2] = bf2f(v.y & 0xffffu); f[3] = bf2f(v.y >> 16);
    f[4] = bf2f(v.z & 0xffffu); f[5] = bf2f(v.z >> 16);
    f[6] = bf2f(v.w & 0xffffu); f[7] = bf2f(v.w >> 16);
}

#define FWHT_SCALE 0.011048543456039806f  // 1/sqrt(8192)

// ---------------- FWHT-4096 on 256 threads x 16 elems (round-11 proven) ----
#define FWHT16(v)                                                         \
    _Pragma("unroll")                                                     \
    for (int hb = 0; hb < 4; ++hb) {                                      \
        const int hh = 1 << hb;                                           \
        _Pragma("unroll")                                                 \
        for (int j = 0; j < 16; ++j)                                      \
            if (!(j & hh)) {                                              \
                float a_ = v[j], b_ = v[j | hh];                          \
                v[j] = a_ + b_; v[j | hh] = a_ - b_;                      \
            }                                                             \
    }

__device__ inline void fwht4096(float* v, float* lds, int t) {
    FWHT16(v)
#pragma unroll
    for (int e = 0; e < 16; ++e) lds[e * 260 + t] = v[e];
    __syncthreads();
    {
        const int base = (t & 15) * 260 + (t >> 4) * 16;
#pragma unroll
        for (int q = 0; q < 4; ++q) {
            float4 f = *reinterpret_cast<const float4*>(&lds[base + q * 4]);
            v[q * 4 + 0] = f.x; v[q * 4 + 1] = f.y;
            v[q * 4 + 2] = f.z; v[q * 4 + 3] = f.w;
        }
    }
    FWHT16(v)
    __syncthreads();
    {
        const int e = t & 15, ub = t >> 4;
#pragma unroll
        for (int i = 0; i < 16; ++i) lds[e * 260 + i * 16 + ub] = v[i];
    }
    __syncthreads();
    {
        const int e = t & 15, i = t >> 4;
#pragma unroll
        for (int ub = 0; ub < 16; ++ub) v[ub] = lds[e * 260 + i * 16 + ub];
    }
    FWHT16(v)
    __syncthreads();
    {
        const int e = t & 15, i = t >> 4;
#pragma unroll
        for (int ub = 0; ub < 16; ++ub) lds[ub * 260 + i * 16 + e] = v[ub];
    }
    __syncthreads();
    {
        const int base = (t >> 4) * 260 + (t & 15) * 16;
#pragma unroll
        for (int q = 0; q < 4; ++q) {
            float4 f = *reinterpret_cast<const float4*>(&lds[base + q * 4]);
            v[q * 4 + 0] = f.x; v[q * 4 + 1] = f.y;
            v[q * 4 + 2] = f.z; v[q * 4 + 3] = f.w;
        }
    }
}

// ---- Kernel A: xt = fwht(input/scaleWH*SU), MFMA-tiled bf16 (r12 proven) --
// Tiled layout: elem (r,k) at ((r>>4)*256 + (k>>5))*512 + ((k&31)>>3)*128
//               + (r&15)*8 + (k&7)   [ushort units]
__global__ __launch_bounds__(256) void k_pre4(const float* __restrict__ in,
                                              const float* __restrict__ scaleWH,
                                              const float* __restrict__ SU,
                                              unsigned short* __restrict__ xt) {
    __shared__ float lds[4160];
    const int r = blockIdx.x, h = blockIdx.y, t = threadIdx.x;
    float v[16];
    const float4* xp = reinterpret_cast<const float4*>(in + (size_t)r * IN_F);
    const float4* sp = reinterpret_cast<const float4*>(scaleWH);
    const float4* up = reinterpret_cast<const float4*>(SU);
#pragma unroll
    for (int q = 0; q < 4; ++q) {
        float4 xl = xp[t * 4 + q],        sl = sp[t * 4 + q],        ul = up[t * 4 + q];
        float4 xh = xp[1024 + t * 4 + q], sh = sp[1024 + t * 4 + q], uh = up[1024 + t * 4 + q];
        float lo0 = xl.x / sl.x * ul.x, hi0 = xh.x / sh.x * uh.x;
        float lo1 = xl.y / sl.y * ul.y, hi1 = xh.y / sh.y * uh.y;
        float lo2 = xl.z / sl.z * ul.z, hi2 = xh.z / sh.z * uh.z;
        float lo3 = xl.w / sl.w * ul.w, hi3 = xh.w / sh.w * uh.w;
        v[q * 4 + 0] = h ? lo0 - hi0 : lo0 + hi0;
        v[q * 4 + 1] = h ? lo1 - hi1 : lo1 + hi1;
        v[q * 4 + 2] = h ? lo2 - hi2 : lo2 + hi2;
        v[q * 4 + 3] = h ? lo3 - hi3 : lo3 + hi3;
    }
    fwht4096(v, lds, t);
    const int ub = t >> 4, i = t & 15;
    const int kblk = h * 128 + ub * 8 + (i >> 1);
    const size_t base = ((size_t)(r >> 4) * 256 + kblk) * 512 + (size_t)(r & 15) * 8;
#pragma unroll
    for (int half = 0; half < 2; ++half) {
        unsigned int w[4];
#pragma unroll
        for (int p = 0; p < 4; ++p) {
            unsigned int lo = f2bf(v[half * 8 + 2 * p]     * FWHT_SCALE);
            unsigned int hi = f2bf(v[half * 8 + 2 * p + 1] * FWHT_SCALE);
            w[p] = lo | (hi << 16);
        }
        const int oct = (i & 1) * 2 + half;
        *reinterpret_cast<uint4*>(xt + base + oct * 128) = make_uint4(w[0], w[1], w[2], w[3]);
    }
}

// ---- Kernel B: A-in-LDS GEMM, barrier-free inner loop ----
// grid (64,16); 512 thr = 8 waves (2 mgrp x 4 ngrp); tile 128x128; K=512 in
// 2 phases. Per phase: stage 64KB A-half via global_load_lds (frag-linear),
// then 8 straight-line iters all-LDS: 4 A ds_read_b128 (conflict-free) +
// 2 cbl gathers (reg indices) + 8 MFMA. Q byte-packed in LDS once -> regs.
__global__ __launch_bounds__(512, 4) void k_gemm18(
        const unsigned short* __restrict__ xt,
        const int* __restrict__ Qidxs,
        const float* __restrict__ cb,
        const float* __restrict__ wscale,
        unsigned short* __restrict__ pout) {
    __shared__ __align__(16) unsigned short cbl[CB][8];   // 4 KB
    __shared__ __align__(16) unsigned short Al[32768];    // 64 KB A phase buf
    __shared__ __align__(16) unsigned int Qb[128 * 16];   // 8 KB packed bytes
    const int tid = threadIdx.x;
    const int wave = tid >> 6, lane = tid & 63;
    const int mgrp = wave & 1, ngrp = wave >> 1;   // 2 m-groups x 4 n-groups
    const int lr = lane & 15, lk8 = lane >> 4;
    const int n0 = blockIdx.x * NTB;
    const int ks0 = blockIdx.y * KSLICE2;
    const int ksb = ks0 >> 5;           // k32-block base in xt tiling
    const int c0 = ks0 >> 3;            // first Qidxs dword col of slice

    // stage A phase p: 64 frags x 1KB; wave w stages rowgrp w, k-blocks 0..7
    auto stageA = [&](int p) {
#pragma unroll
        for (int j = 0; j < 8; ++j) {
            const unsigned short* g = xt
                + ((size_t)(wave * 256 + ksb + p * 8 + j)) * 512 + lane * 8;
            as3v l = (as3v)(Al + (wave * 8 + j) * 512);
            __builtin_amdgcn_global_load_lds((as1cv)(const void*)g, l, 16, 0, 0);
        }
    };

    // ---- one-time: byte-pack Q slice (128 rows x 64 dword-cols -> 8KB) ----
    // byte pos(row, c) = row*64 + (c&3)*16 + (c>>5)*8 + ((c>>2)&7)
    // so lane (lr,lk8) gets its 16 indices {c = ph*32+it*4+lk8} in 4 dwords.
    {
        const int row = tid >> 2, qq = tid & 3;   // 4 threads/row, 16 cols each
        const int* g = Qidxs + (size_t)(n0 + row) * QC + c0 + qq * 16;
        int qv[16];
#pragma unroll
        for (int j4 = 0; j4 < 4; ++j4) {
            int4 vv = *reinterpret_cast<const int4*>(g + j4 * 4);
            qv[j4 * 4 + 0] = vv.x; qv[j4 * 4 + 1] = vv.y;
            qv[j4 * 4 + 2] = vv.z; qv[j4 * 4 + 3] = vv.w;
        }
#pragma unroll
        for (int m3 = 0; m3 < 4; ++m3) {
            unsigned int D = (unsigned int)(qv[m3] & 255)
                           | ((unsigned int)(qv[m3 + 4] & 255) << 8)
                           | ((unsigned int)(qv[m3 + 8] & 255) << 16)
                           | ((unsigned int)(qv[m3 + 12] & 255) << 24);
            Qb[row * 16 + m3 * 4 + (qq >> 1) * 2 + (qq & 1)] = D;
        }
    }
    stageA(0);
    const float wsc = wscale[0];
    for (int e = tid; e < CB * 8; e += 512) cbl[e >> 3][e & 7] = f2bf(cb[e] * wsc);

    f32x4 acc[4][2];
#pragma unroll
    for (int mt = 0; mt < 4; ++mt)
#pragma unroll
        for (int nt = 0; nt < 2; ++nt) acc[mt][nt] = (f32x4){0.f, 0.f, 0.f, 0.f};

    __syncthreads();     // Qb + cbl + A phase 0 staged

    // pull all 16 per-lane indices (2 n-blocks x 2 phases x 8 iters) to regs
    unsigned int qr[2][4];
#pragma unroll
    for (int nb = 0; nb < 2; ++nb) {
        const int qrow = ngrp * 32 + nb * 16 + lr;
#pragma unroll
        for (int d = 0; d < 4; ++d) qr[nb][d] = Qb[qrow * 16 + lk8 * 4 + d];
    }

#define PHASE(PH)                                                             \
    _Pragma("unroll")                                                         \
    for (int it = 0; it < 8; ++it) {                                          \
        const int dsel = (PH) * 2 + (it >> 2), sh = (it & 3) * 8;             \
        bf8 b0 = *(const bf8*)&cbl[(qr[0][dsel] >> sh) & 255][0];             \
        bf8 b1 = *(const bf8*)&cbl[(qr[1][dsel] >> sh) & 255][0];             \
        bf8 a0 = *(const bf8*)(Al + ((mgrp * 4 + 0) * 8 + it) * 512 + lane * 8); \
        bf8 a1 = *(const bf8*)(Al + ((mgrp * 4 + 1) * 8 + it) * 512 + lane * 8); \
        bf8 a2 = *(const bf8*)(Al + ((mgrp * 4 + 2) * 8 + it) * 512 + lane * 8); \
        bf8 a3 = *(const bf8*)(Al + ((mgrp * 4 + 3) * 8 + it) * 512 + lane * 8); \
        acc[0][0] = __builtin_amdgcn_mfma_f32_16x16x32_bf16(a0, b0, acc[0][0], 0, 0, 0); \
        acc[0][1] = __builtin_amdgcn_mfma_f32_16x16x32_bf16(a0, b1, acc[0][1], 0, 0, 0); \
        acc[1][0] = __builtin_amdgcn_mfma_f32_16x16x32_bf16(a1, b0, acc[1][0], 0, 0, 0); \
        acc[1][1] = __builtin_amdgcn_mfma_f32_16x16x32_bf16(a1, b1, acc[1][1], 0, 0, 0); \
        acc[2][0] = __builtin_amdgcn_mfma_f32_16x16x32_bf16(a2, b0, acc[2][0], 0, 0, 0); \
        acc[2][1] = __builtin_amdgcn_mfma_f32_16x16x32_bf16(a2, b1, acc[2][1], 0, 0, 0); \
        acc[3][0] = __builtin_amdgcn_mfma_f32_16x16x32_bf16(a3, b0, acc[3][0], 0, 0, 0); \
        acc[3][1] = __builtin_amdgcn_mfma_f32_16x16x32_bf16(a3, b1, acc[3][1], 0, 0, 0); \
    }

    PHASE(0)
    __syncthreads();     // all waves done reading A phase 0
    stageA(1);
    __syncthreads();     // A phase 1 staged
    PHASE(1)
#undef PHASE

    // epilogue: C/D col=lane&15, row=(lane>>4)*4+reg; bf16 partial store
    unsigned short* ps = pout + (size_t)blockIdx.y * (NROWS * OUT_F);
#pragma unroll
    for (int mt = 0; mt < 4; ++mt) {
        const int row = mgrp * 64 + mt * 16 + lk8 * 4;
#pragma unroll
        for (int nt = 0; nt < 2; ++nt) {
            const int col = n0 + ngrp * 32 + nt * 16 + lr;
#pragma unroll
            for (int r2 = 0; r2 < 4; ++r2)
                ps[(size_t)(row + r2) * OUT_F + col] = f2bf(acc[mt][nt][r2]);
        }
    }
}

// ---- Kernel C: out = fwht(sum of 16 slices)*SV + bias, grid (128,2) ----
__global__ __launch_bounds__(256) void k_post5(const unsigned short* __restrict__ pin,
                                               const float* __restrict__ SV,
                                               const float* __restrict__ bias,
                                               float* __restrict__ out) {
    __shared__ float lds[4160];
    const int r = blockIdx.x, h = blockIdx.y, t = threadIdx.x;
    float lo[16], hi[16], v[16];
#pragma unroll
    for (int j = 0; j < 16; ++j) { lo[j] = 0.f; hi[j] = 0.f; }
#pragma unroll 1
    for (int sl = 0; sl < NSLT; ++sl) {
        const uint4* pl = reinterpret_cast<const uint4*>(
            pin + (size_t)sl * NROWS * OUT_F + (size_t)r * OUT_F + t * 16);
        const uint4* ph = reinterpret_cast<const uint4*>(
            pin + (size_t)sl * NROWS * OUT_F + (size_t)r * OUT_F + 4096 + t * 16);
        float a[8], b[8];
        unpack8(pl[0], a); unpack8(pl[1], b);
#pragma unroll
        for (int j = 0; j < 8; ++j) { lo[j] += a[j]; lo[8 + j] += b[j]; }
        unpack8(ph[0], a); unpack8(ph[1], b);
#pragma unroll
        for (int j = 0; j < 8; ++j) { hi[j] += a[j]; hi[8 + j] += b[j]; }
    }
#pragma unroll
    for (int j = 0; j < 16; ++j) v[j] = h ? lo[j] - hi[j] : lo[j] + hi[j];
    fwht4096(v, lds, t);
    const int cb4 = (h * 4096 + (t >> 4) * 256 + (t & 15) * 16) >> 2;
    const float4* svp = reinterpret_cast<const float4*>(SV);
    const float4* bip = reinterpret_cast<const float4*>(bias);
    float4* op = reinterpret_cast<float4*>(out + (size_t)r * OUT_F);
#pragma unroll
    for (int q = 0; q < 4; ++q) {
        float4 sv = svp[cb4 + q], bi = bip[cb4 + q], o;
        o.x = v[q * 4 + 0] * FWHT_SCALE * sv.x + bi.x;
        o.y = v[q * 4 + 1] * FWHT_SCALE * sv.y + bi.y;
        o.z = v[q * 4 + 2] * FWHT_SCALE * sv.z + bi.z;
        o.w = v[q * 4 + 3] * FWHT_SCALE * sv.w + bi.w;
        op[cb4 + q] = o;
    }
}

extern "C" void kernel_launch(void* const* d_in, const int* in_sizes, int n_in,
                              void* d_out, int out_size, void* d_ws, size_t ws_size,
                              hipStream_t stream) {
    const float* in      = (const float*)d_in[0];
    const int*   Qidxs   = (const int*)d_in[1];
    const float* cb      = (const float*)d_in[2];
    const float* scaleWH = (const float*)d_in[3];
    const float* SU      = (const float*)d_in[4];
    const float* SV      = (const float*)d_in[5];
    const float* wscale  = (const float*)d_in[6];
    const float* bias    = (const float*)d_in[7];
    float* out = (float*)d_out;

    unsigned short* xt    = (unsigned short*)d_ws;                    // 2 MB (tiled)
    unsigned short* parts = (unsigned short*)((char*)d_ws
                            + (size_t)NROWS * IN_F * 2);              // 32 MB (16 slices)

    k_pre4<<<dim3(NROWS, 2), 256, 0, stream>>>(in, scaleWH, SU, xt);
    k_gemm18<<<dim3(OUT_F / NTB, NSL2), 512, 0, stream>>>(xt, Qidxs, cb, wscale, parts);
    k_post5<<<dim3(NROWS, 2), 256, 0, stream>>>(parts, SV, bias, out);
}

// Round 20
// 46.342 us; speedup vs baseline: 1.4523x; 1.1907x over previous
//
#include <hip/hip_runtime.h>
#include <hip/hip_bf16.h>

#define IN_F 8192
#define OUT_F 8192
#define NROWS 128
#define CB 256
#define NSL 8                  // split-K slices
#define KSLICE (IN_F / NSL)    // 1024
#define NTB 128                // n-tile per block
#define QC (IN_F / 8)          // 1024 dwords per Qidxs row

using bf8   = __attribute__((ext_vector_type(8))) short;  // 8 bf16 (4 VGPRs)
using f32x4 = __attribute__((ext_vector_type(4))) float;  // 4 fp32 accum

typedef const __attribute__((address_space(1))) void* as1cv;
typedef __attribute__((address_space(3))) void* as3v;

__device__ inline float bf2f(unsigned int u) {
    union { unsigned int i; float f; } v; v.i = u << 16; return v.f;
}
__device__ inline unsigned short f2bf(float f) {
    __hip_bfloat16 h = __float2bfloat16(f);
    return *reinterpret_cast<unsigned short*>(&h);
}
__device__ inline void unpack8(uint4 v, float* f) {
    f[0] = bf2f(v.x & 0xffffu); f[1] = bf2f(v.x >> 16);
    f[2] = bf2f(v.y & 0xffffu); f[3] = bf2f(v.y >> 16);
    f[4] = bf2f(v.z & 0xffffu); f[5] = bf2f(v.z >> 16);
    f[6] = bf2f(v.w & 0xffffu); f[7] = bf2f(v.w >> 16);
}

#define FWHT_SCALE 0.011048543456039806f  // 1/sqrt(8192)

// ---------------- FWHT-4096 on 256 threads x 16 elems (round-11 proven) ----
#define FWHT16(v)                                                         \
    _Pragma("unroll")                                                     \
    for (int hb = 0; hb < 4; ++hb) {                                      \
        const int hh = 1 << hb;                                           \
        _Pragma("unroll")                                                 \
        for (int j = 0; j < 16; ++j)                                      \
            if (!(j & hh)) {                                              \
                float a_ = v[j], b_ = v[j | hh];                          \
                v[j] = a_ + b_; v[j | hh] = a_ - b_;                      \
            }                                                             \
    }

__device__ inline void fwht4096(float* v, float* lds, int t) {
    FWHT16(v)
#pragma unroll
    for (int e = 0; e < 16; ++e) lds[e * 260 + t] = v[e];
    __syncthreads();
    {
        const int base = (t & 15) * 260 + (t >> 4) * 16;
#pragma unroll
        for (int q = 0; q < 4; ++q) {
            float4 f = *reinterpret_cast<const float4*>(&lds[base + q * 4]);
            v[q * 4 + 0] = f.x; v[q * 4 + 1] = f.y;
            v[q * 4 + 2] = f.z; v[q * 4 + 3] = f.w;
        }
    }
    FWHT16(v)
    __syncthreads();
    {
        const int e = t & 15, ub = t >> 4;
#pragma unroll
        for (int i = 0; i < 16; ++i) lds[e * 260 + i * 16 + ub] = v[i];
    }
    __syncthreads();
    {
        const int e = t & 15, i = t >> 4;
#pragma unroll
        for (int ub = 0; ub < 16; ++ub) v[ub] = lds[e * 260 + i * 16 + ub];
    }
    FWHT16(v)
    __syncthreads();
    {
        const int e = t & 15, i = t >> 4;
#pragma unroll
        for (int ub = 0; ub < 16; ++ub) lds[ub * 260 + i * 16 + e] = v[ub];
    }
    __syncthreads();
    {
        const int base = (t >> 4) * 260 + (t & 15) * 16;
#pragma unroll
        for (int q = 0; q < 4; ++q) {
            float4 f = *reinterpret_cast<const float4*>(&lds[base + q * 4]);
            v[q * 4 + 0] = f.x; v[q * 4 + 1] = f.y;
            v[q * 4 + 2] = f.z; v[q * 4 + 3] = f.w;
        }
    }
}

// ---- Kernel A: xt = fwht(input/scaleWH*SU), MFMA-tiled bf16, grid (128,2) --
// Tiled layout: elem (r,k) at ((r>>4)*256 + (k>>5))*512 + ((k&31)>>3)*128
//               + (r&15)*8 + (k&7)   [ushort units]
__global__ __launch_bounds__(256) void k_pre4(const float* __restrict__ in,
                                              const float* __restrict__ scaleWH,
                                              const float* __restrict__ SU,
                                              unsigned short* __restrict__ xt) {
    __shared__ float lds[4160];
    const int r = blockIdx.x, h = blockIdx.y, t = threadIdx.x;
    float v[16];
    const float4* xp = reinterpret_cast<const float4*>(in + (size_t)r * IN_F);
    const float4* sp = reinterpret_cast<const float4*>(scaleWH);
    const float4* up = reinterpret_cast<const float4*>(SU);
#pragma unroll
    for (int q = 0; q < 4; ++q) {
        float4 xl = xp[t * 4 + q],        sl = sp[t * 4 + q],        ul = up[t * 4 + q];
        float4 xh = xp[1024 + t * 4 + q], sh = sp[1024 + t * 4 + q], uh = up[1024 + t * 4 + q];
        float lo0 = xl.x / sl.x * ul.x, hi0 = xh.x / sh.x * uh.x;
        float lo1 = xl.y / sl.y * ul.y, hi1 = xh.y / sh.y * uh.y;
        float lo2 = xl.z / sl.z * ul.z, hi2 = xh.z / sh.z * uh.z;
        float lo3 = xl.w / sl.w * ul.w, hi3 = xh.w / sh.w * uh.w;
        v[q * 4 + 0] = h ? lo0 - hi0 : lo0 + hi0;
        v[q * 4 + 1] = h ? lo1 - hi1 : lo1 + hi1;
        v[q * 4 + 2] = h ? lo2 - hi2 : lo2 + hi2;
        v[q * 4 + 3] = h ? lo3 - hi3 : lo3 + hi3;
    }
    fwht4096(v, lds, t);
    const int ub = t >> 4, i = t & 15;
    const int kblk = h * 128 + ub * 8 + (i >> 1);
    const size_t base = ((size_t)(r >> 4) * 256 + kblk) * 512 + (size_t)(r & 15) * 8;
#pragma unroll
    for (int half = 0; half < 2; ++half) {
        unsigned int w[4];
#pragma unroll
        for (int p = 0; p < 4; ++p) {
            unsigned int lo = f2bf(v[half * 8 + 2 * p]     * FWHT_SCALE);
            unsigned int hi = f2bf(v[half * 8 + 2 * p + 1] * FWHT_SCALE);
            w[p] = lo | (hi << 16);
        }
        const int oct = (i & 1) * 2 + half;
        *reinterpret_cast<uint4*>(xt + base + oct * 128) = make_uint4(w[0], w[1], w[2], w[3]);
    }
}

// ---- Kernel B: GEMM, 512 thr = 8 waves (4 wave-rows x 2 wave-cols) ----
// grid (64, NSL); block tile 128x128; K-step 32; A dup 2x (L2 256MB).
// Qidxs chunks (128 x 64 dwords, 32KB) double-buffered via global_load_lds;
// barriers only at chunk boundaries (drain loads issued a full chunk ago).
// (round-12 measured best: total 46.3us, gemm ~34us = 506 TF)
__global__ __launch_bounds__(512, 4) void k_gemm9(
        const unsigned short* __restrict__ xt,
        const int* __restrict__ Qidxs,
        const float* __restrict__ cb,
        const float* __restrict__ wscale,
        unsigned short* __restrict__ pout) {
    __shared__ __align__(16) unsigned short cbl[CB][8];   // 4 KB
    __shared__ __align__(16) int Qlds[2][128 * 64];       // 2 x 32 KB
    const int tid = threadIdx.x;
    const int wave = tid >> 6, lane = tid & 63;
    const int wr = wave & 3, wc = wave >> 2;     // 4 wave-rows x 2 wave-cols
    const int lr = lane & 15, lk8 = lane >> 4;
    const int n0 = blockIdx.x * NTB;
    const int ks0 = blockIdx.y * KSLICE;
    const int ksb = ks0 >> 5;
    const int c0 = ks0 >> 3;

    auto stageQ = [&](int buf, int ch) {
#pragma unroll
        for (int j = 0; j < 4; ++j) {
            const int row = j * 32 + wave * 4 + (lane >> 4);
            const int cgs = (lane & 15) ^ (row & 15);
            const int* g = Qidxs + (size_t)(n0 + row) * QC + c0 + ch * 64 + cgs * 4;
            as3v l = (as3v)(&Qlds[buf][(j * 32 + wave * 4) * 64]);
            __builtin_amdgcn_global_load_lds((as1cv)(const void*)g, l, 16, 0, 0);
        }
    };

    stageQ(0, 0);
    const float wsc = wscale[0];
    for (int e = tid; e < CB * 8; e += 512) cbl[e >> 3][e & 7] = f2bf(cb[e] * wsc);

    f32x4 acc[2][4];
#pragma unroll
    for (int mt = 0; mt < 2; ++mt)
#pragma unroll
        for (int nt = 0; nt < 4; ++nt) acc[mt][nt] = (f32x4){0.f, 0.f, 0.f, 0.f};

    // A (tiled layout): frag (m-block wr*2+mt, k-block ksb+it) contiguous 1KB
    const unsigned short* xw = xt + ((size_t)(wr * 2) * 256 + ksb) * 512 + lane * 8;
    __syncthreads();          // cbl + chunk 0 staged
    stageQ(1, 1);             // chunk 1 in flight across chunk 0 compute

#define CHUNK(BUF, CH)                                                        \
    _Pragma("unroll")                                                         \
    for (int itc = 0; itc < 16; ++itc) {                                      \
        const int it = (CH) * 16 + itc;                                       \
        const int qcol = ((itc ^ lr) << 2) + lk8;                             \
        const int qv0 = Qlds[BUF][(wc * 64 +  0 + lr) * 64 + qcol];           \
        const int qv1 = Qlds[BUF][(wc * 64 + 16 + lr) * 64 + qcol];           \
        const int qv2 = Qlds[BUF][(wc * 64 + 32 + lr) * 64 + qcol];           \
        const int qv3 = Qlds[BUF][(wc * 64 + 48 + lr) * 64 + qcol];           \
        bf8 a0 = *reinterpret_cast<const bf8*>(xw + ((size_t)(0 * 256) + it) * 512); \
        bf8 a1 = *reinterpret_cast<const bf8*>(xw + ((size_t)(1 * 256) + it) * 512); \
        bf8 b0 = *(const bf8*)&cbl[qv0][0];                                   \
        bf8 b1 = *(const bf8*)&cbl[qv1][0];                                   \
        bf8 b2 = *(const bf8*)&cbl[qv2][0];                                   \
        bf8 b3 = *(const bf8*)&cbl[qv3][0];                                   \
        acc[0][0] = __builtin_amdgcn_mfma_f32_16x16x32_bf16(a0, b0, acc[0][0], 0, 0, 0); \
        acc[0][1] = __builtin_amdgcn_mfma_f32_16x16x32_bf16(a0, b1, acc[0][1], 0, 0, 0); \
        acc[0][2] = __builtin_amdgcn_mfma_f32_16x16x32_bf16(a0, b2, acc[0][2], 0, 0, 0); \
        acc[0][3] = __builtin_amdgcn_mfma_f32_16x16x32_bf16(a0, b3, acc[0][3], 0, 0, 0); \
        acc[1][0] = __builtin_amdgcn_mfma_f32_16x16x32_bf16(a1, b0, acc[1][0], 0, 0, 0); \
        acc[1][1] = __builtin_amdgcn_mfma_f32_16x16x32_bf16(a1, b1, acc[1][1], 0, 0, 0); \
        acc[1][2] = __builtin_amdgcn_mfma_f32_16x16x32_bf16(a1, b2, acc[1][2], 0, 0, 0); \
        acc[1][3] = __builtin_amdgcn_mfma_f32_16x16x32_bf16(a1, b3, acc[1][3], 0, 0, 0); \
    }

    CHUNK(0, 0)
    __syncthreads();          // drains stage(1) — issued a full chunk ago
    CHUNK(1, 1)
#undef CHUNK

    // epilogue: C/D col=lane&15, row=(lane>>4)*4+reg; bf16 partial store
    unsigned short* ps = pout + (size_t)blockIdx.y * (NROWS * OUT_F);
#pragma unroll
    for (int mt = 0; mt < 2; ++mt) {
        const int row = wr * 32 + mt * 16 + lk8 * 4;
#pragma unroll
        for (int nt = 0; nt < 4; ++nt) {
            const int col = n0 + wc * 64 + nt * 16 + lr;
#pragma unroll
            for (int r2 = 0; r2 < 4; ++r2)
                ps[(size_t)(row + r2) * OUT_F + col] = f2bf(acc[mt][nt][r2]);
        }
    }
}

// ---- Kernel C: out = fwht(sum_slices)*SV + bias, grid (128,2), f32 out ----
__global__ __launch_bounds__(256) void k_post4(const unsigned short* __restrict__ pin,
                                               const float* __restrict__ SV,
                                               const float* __restrict__ bias,
                                               float* __restrict__ out) {
    __shared__ float lds[4160];
    const int r = blockIdx.x, h = blockIdx.y, t = threadIdx.x;
    float lo[16], hi[16], v[16];
#pragma unroll
    for (int j = 0; j < 16; ++j) { lo[j] = 0.f; hi[j] = 0.f; }
#pragma unroll 1
    for (int sl = 0; sl < NSL; ++sl) {
        const uint4* pl = reinterpret_cast<const uint4*>(
            pin + (size_t)sl * NROWS * OUT_F + (size_t)r * OUT_F + t * 16);
        const uint4* ph = reinterpret_cast<const uint4*>(
            pin + (size_t)sl * NROWS * OUT_F + (size_t)r * OUT_F + 4096 + t * 16);
        float a[8], b[8];
        unpack8(pl[0], a); unpack8(pl[1], b);
#pragma unroll
        for (int j = 0; j < 8; ++j) { lo[j] += a[j]; lo[8 + j] += b[j]; }
        unpack8(ph[0], a); unpack8(ph[1], b);
#pragma unroll
        for (int j = 0; j < 8; ++j) { hi[j] += a[j]; hi[8 + j] += b[j]; }
    }
#pragma unroll
    for (int j = 0; j < 16; ++j) v[j] = h ? lo[j] - hi[j] : lo[j] + hi[j];
    fwht4096(v, lds, t);
    const int cb4 = (h * 4096 + (t >> 4) * 256 + (t & 15) * 16) >> 2;
    const float4* svp = reinterpret_cast<const float4*>(SV);
    const float4* bip = reinterpret_cast<const float4*>(bias);
    float4* op = reinterpret_cast<float4*>(out + (size_t)r * OUT_F);
#pragma unroll
    for (int q = 0; q < 4; ++q) {
        float4 sv = svp[cb4 + q], bi = bip[cb4 + q], o;
        o.x = v[q * 4 + 0] * FWHT_SCALE * sv.x + bi.x;
        o.y = v[q * 4 + 1] * FWHT_SCALE * sv.y + bi.y;
        o.z = v[q * 4 + 2] * FWHT_SCALE * sv.z + bi.z;
        o.w = v[q * 4 + 3] * FWHT_SCALE * sv.w + bi.w;
        op[cb4 + q] = o;
    }
}

extern "C" void kernel_launch(void* const* d_in, const int* in_sizes, int n_in,
                              void* d_out, int out_size, void* d_ws, size_t ws_size,
                              hipStream_t stream) {
    const float* in      = (const float*)d_in[0];
    const int*   Qidxs   = (const int*)d_in[1];
    const float* cb      = (const float*)d_in[2];
    const float* scaleWH = (const float*)d_in[3];
    const float* SU      = (const float*)d_in[4];
    const float* SV      = (const float*)d_in[5];
    const float* wscale  = (const float*)d_in[6];
    const float* bias    = (const float*)d_in[7];
    float* out = (float*)d_out;

    unsigned short* xt    = (unsigned short*)d_ws;                    // 2 MB (tiled)
    unsigned short* parts = (unsigned short*)((char*)d_ws
                            + (size_t)NROWS * IN_F * 2);              // 16 MB

    k_pre4<<<dim3(NROWS, 2), 256, 0, stream>>>(in, scaleWH, SU, xt);
    k_gemm9<<<dim3(OUT_F / NTB, NSL), 512, 0, stream>>>(xt, Qidxs, cb, wscale, parts);
    k_post4<<<dim3(NROWS, 2), 256, 0, stream>>>(parts, SV, bias, out);
}